// Round 1
// baseline (51.149 us; speedup 1.0000x reference)
//
#include <hip/hip_runtime.h>
#include <math.h>

#define B_    48
#define N_    512
#define NBOND 4096
#define H_    8
#define L_    2

__device__ __forceinline__ float sigf(float x) { return 1.0f / (1.0f + expf(-x)); }

__device__ __forceinline__ float taperf(float r) {
    const float rmin = 0.001f, rmax = 0.002f;
    const float d = rmin - rmax;
    const float rterm = 1.0f / (d * d * d);
    float r3  = (r > rmax) ? 1.0f : 0.0f;
    bool ok   = (r <= rmax) && (r > rmin);
    float r2  = ok ? r : 0.0f;
    float r20 = ok ? 1.0f : 0.0f;
    float rm   = rmin * r20;
    float rd   = rm - r2;
    float trm1 = rm + 2.0f * r2 - 3.0f * rmax * r20;
    return rterm * rd * rd * trm1 + r3;
}

// block-wide sum (256 threads = 4 waves); returns total in thread 0 only
__device__ __forceinline__ float block_sum_256(float v) {
    for (int off = 32; off > 0; off >>= 1) v += __shfl_down(v, off, 64);
    __shared__ float smem[4];
    int lane = threadIdx.x & 63, wid = threadIdx.x >> 6;
    if (lane == 0) smem[wid] = v;
    __syncthreads();
    float s = 0.0f;
    if (threadIdx.x == 0) s = smem[0] + smem[1] + smem[2] + smem[3];
    return s;
}

__global__ __launch_bounds__(256) void bond_kernel(
    const float* __restrict__ x, const float* __restrict__ cell, const float* __restrict__ rcell,
    const int*  __restrict__ bdid,
    const float* __restrict__ rosi, const float* __restrict__ bo1, const float* __restrict__ bo2,
    const float* __restrict__ ropi, const float* __restrict__ bo3, const float* __restrict__ bo4,
    const float* __restrict__ ropp, const float* __restrict__ bo5, const float* __restrict__ bo6,
    const float* __restrict__ Desi,
    const float* __restrict__ wi, const float* __restrict__ w, const float* __restrict__ bvec,
    const float* __restrict__ wo, const float* __restrict__ bo_out,
    float* __restrict__ Delta, float* __restrict__ Dpi, float* __restrict__ SO,
    float* __restrict__ acc)
{
    int tid = blockIdx.x * 256 + threadIdx.x;
    int b = tid >> 12;        // / NBOND
    int k = tid & (NBOND - 1);
    int t = (k < 1600) ? 0 : ((k < 3200) ? 1 : 2);

    int i = bdid[2 * k + 0];
    int j = bdid[2 * k + 1];

    const float* xb = x + (size_t)b * (N_ * 3);
    float vx = xb[3 * i + 0] - xb[3 * j + 0];
    float vy = xb[3 * i + 1] - xb[3 * j + 1];
    float vz = xb[3 * i + 2] - xb[3 * j + 2];

    // vrf = vr @ rcell  (general 3x3, matches reference exactly)
    float f0 = vx * rcell[0] + vy * rcell[3] + vz * rcell[6];
    float f1 = vx * rcell[1] + vy * rcell[4] + vz * rcell[7];
    float f2 = vx * rcell[2] + vy * rcell[5] + vz * rcell[8];
    f0 = (f0 - 0.5f > 0.0f) ? f0 - 1.0f : f0;  f0 = (f0 + 0.5f < 0.0f) ? f0 + 1.0f : f0;
    f1 = (f1 - 0.5f > 0.0f) ? f1 - 1.0f : f1;  f1 = (f1 + 0.5f < 0.0f) ? f1 + 1.0f : f1;
    f2 = (f2 - 0.5f > 0.0f) ? f2 - 1.0f : f2;  f2 = (f2 + 0.5f < 0.0f) ? f2 + 1.0f : f2;
    float wx = f0 * cell[0] + f1 * cell[3] + f2 * cell[6];
    float wy = f0 * cell[1] + f1 * cell[4] + f2 * cell[7];
    float wz = f0 * cell[2] + f1 * cell[5] + f2 * cell[8];
    float r = sqrtf(wx * wx + wy * wy + wz * wz);

    // bond order terms
    float e1 = 1.001f * expf(bo1[t] * powf(r / rosi[t], bo2[t]));
    float e2 = expf(bo3[t] * powf(r / ropi[t], bo4[t]));
    float e3 = expf(bo5[t] * powf(r / ropp[t], bo6[t]));
    float bosi = taperf(e1) * (e1 - 0.001f);
    float bopi = taperf(e2) * e2;
    float bopp = taperf(e3) * e3;

    // MLP: 3 -> 8 -> (8 -> 8) x2 -> 1, all sigmoid
    float h[H_], h2[H_];
    #pragma unroll
    for (int hh = 0; hh < H_; ++hh) {
        float s = bosi * wi[t * 24 + 0 * H_ + hh]
                + bopi * wi[t * 24 + 1 * H_ + hh]
                + bopp * wi[t * 24 + 2 * H_ + hh];
        h[hh] = sigf(s);
    }
    #pragma unroll
    for (int l = 0; l < L_; ++l) {
        #pragma unroll
        for (int ho = 0; ho < H_; ++ho) {
            float s = bvec[t * (L_ * H_) + l * H_ + ho];
            #pragma unroll
            for (int hi = 0; hi < H_; ++hi)
                s += h[hi] * w[t * (L_ * H_ * H_) + l * (H_ * H_) + hi * H_ + ho];
            h2[ho] = sigf(s);
        }
        #pragma unroll
        for (int hh = 0; hh < H_; ++hh) h[hh] = h2[hh];
    }
    float o = bo_out[t];
    #pragma unroll
    for (int hi = 0; hi < H_; ++hi) o += h[hi] * wo[t * H_ + hi];
    float esi = sigf(o);
    float ebd = -Desi[t] * esi;

    float bo_sum = bosi + bopi + bopp;
    float bpi    = bopi + bopp;

    float* Db = Delta + (size_t)b * N_;
    float* Pb = Dpi   + (size_t)b * N_;
    float* Sb = SO    + (size_t)b * N_;
    atomicAdd(&Db[i], bo_sum); atomicAdd(&Db[j], bo_sum);
    atomicAdd(&Pb[i], bpi);    atomicAdd(&Pb[j], bpi);
    atomicAdd(&Sb[i], bosi);   atomicAdd(&Sb[j], bosi);

    float bs = block_sum_256(ebd);
    if (threadIdx.x == 0) atomicAdd(&acc[b], bs);
}

__global__ __launch_bounds__(256) void atom_kernel(
    const int* __restrict__ atype,
    const float* __restrict__ sval, const float* __restrict__ svale, const float* __restrict__ slp2,
    const float* __restrict__ sov2, const float* __restrict__ sov5,
    const float* __restrict__ Delta, const float* __restrict__ Dpi, const float* __restrict__ SO,
    float* __restrict__ acc)
{
    int tid = blockIdx.x * 256 + threadIdx.x;
    int b = tid >> 9;        // / N_
    int n = tid & (N_ - 1);

    int at = atype[n];
    float val  = sval[at];
    float vale = svale[at];
    float lp2  = slp2[at];
    float ov2  = sov2[at];
    float ov5  = sov5[at];

    float D   = Delta[(size_t)b * N_ + n];
    float DP  = Dpi  [(size_t)b * N_ + n];
    float so  = SO   [(size_t)b * N_ + n];

    float Nlp = 0.5f * (vale - val);
    float de  = 0.5f * (D - vale);
    float De  = fminf(ceilf(de), 0.0f);            // -relu(-ceil(de))
    float t1  = 1.0f + de - De;
    float nlp = -De + expf(-40.0f * t1 * t1);      // LP1*4 = 40
    float Dlp = fmaxf(Nlp - nlp + 1.0f, 0.0f) - 1.0f;
    float Elone = lp2 * Dlp / (1.0f + expf(-75.0f * Dlp));

    float dlc = D - val - Dlp / (1.0f + 5.0f * expf(3.0f * DP));   // OVUN3=5, OVUN4=3
    float denom = dlc + val;
    float ot = 1.0f / ((denom != 0.0f) ? denom : 1e-8f);
    float Eover = so * ot * dlc * sigf(-ov2 * dlc);

    float expeu1 = expf(6.0f * dlc);               // OVUN6=6
    float eu1 = sigf(ov2 * dlc);
    float eu2 = 1.0f / (1.0f + 1.0f * expf(12.0f * DP));  // OVUN7=1, OVUN8=12
    float Eunder = -ov5 * (1.0f - expeu1) * eu1 * eu2;

    float e = Elone + Eover + Eunder;
    float bs = block_sum_256(e);
    if (threadIdx.x == 0) atomicAdd(&acc[b], bs);
}

__global__ void finish_kernel(const float* __restrict__ acc, float* __restrict__ out) {
    int t = threadIdx.x;
    if (t < B_) out[t] = acc[t];
}

extern "C" void kernel_launch(void* const* d_in, const int* in_sizes, int n_in,
                              void* d_out, int out_size, void* d_ws, size_t ws_size,
                              hipStream_t stream)
{
    const float* x     = (const float*)d_in[0];
    const float* cell  = (const float*)d_in[1];
    const float* rcell = (const float*)d_in[2];
    const int*   bdid  = (const int*)d_in[3];
    const int*   atype = (const int*)d_in[4];
    const float* rosi  = (const float*)d_in[5];
    const float* bo1   = (const float*)d_in[6];
    const float* bo2   = (const float*)d_in[7];
    const float* ropi  = (const float*)d_in[8];
    const float* bo3   = (const float*)d_in[9];
    const float* bo4   = (const float*)d_in[10];
    const float* ropp  = (const float*)d_in[11];
    const float* bo5   = (const float*)d_in[12];
    const float* bo6   = (const float*)d_in[13];
    const float* Desi  = (const float*)d_in[14];
    const float* sval  = (const float*)d_in[15];
    const float* svale = (const float*)d_in[16];
    const float* slp2  = (const float*)d_in[17];
    const float* sov2  = (const float*)d_in[18];
    const float* sov5  = (const float*)d_in[19];
    const float* wi    = (const float*)d_in[20];
    const float* w     = (const float*)d_in[21];
    const float* bvec  = (const float*)d_in[22];
    const float* wo    = (const float*)d_in[23];
    const float* bo_o  = (const float*)d_in[24];
    float* out = (float*)d_out;

    float* Delta = (float*)d_ws;
    float* Dpi   = Delta + (size_t)B_ * N_;
    float* SO    = Dpi   + (size_t)B_ * N_;
    float* acc   = SO    + (size_t)B_ * N_;
    size_t zbytes = ((size_t)3 * B_ * N_ + B_) * sizeof(float);
    hipMemsetAsync(d_ws, 0, zbytes, stream);

    bond_kernel<<<(B_ * NBOND) / 256, 256, 0, stream>>>(
        x, cell, rcell, bdid,
        rosi, bo1, bo2, ropi, bo3, bo4, ropp, bo5, bo6, Desi,
        wi, w, bvec, wo, bo_o,
        Delta, Dpi, SO, acc);

    atom_kernel<<<(B_ * N_) / 256, 256, 0, stream>>>(
        atype, sval, svale, slp2, sov2, sov5,
        Delta, Dpi, SO, acc);

    finish_kernel<<<1, 64, 0, stream>>>(acc, out);
}